// Round 5
// baseline (265.397 us; speedup 1.0000x reference)
//
#include <hip/hip_runtime.h>
#include <hip/hip_fp8.h>

#define N_NODES 50000
#define N_EDGES 800000
#define D 128
#define NBUK 782         // 64-node dst buckets = grid size (all co-resident)
#define CAPB 1344        // edges per bucket cap (mean ~1023, +10 sigma)
#define SRTN (CAPB + 64*3)   // 1536 u16 entries, pad-to-4 worst case
#define EPB 1024         // edges per block: 782*1024 = 800768 >= 800000
#define CURS 16          // gcursor stride in ints: one counter per 64B line

typedef __bf16 bf16x8 __attribute__((ext_vector_type(8)));
typedef __bf16 bf16x4 __attribute__((ext_vector_type(4)));
typedef float  f32x4  __attribute__((ext_vector_type(4)));
typedef float  f32x2  __attribute__((ext_vector_type(2)));

#if defined(__has_builtin)
#if __has_builtin(__builtin_amdgcn_cvt_pk_f32_fp8) && __has_builtin(__builtin_amdgcn_cvt_pk_fp8_f32)
#define HW_FP8 1
#endif
#endif

// ws layout (bytes):
//   gcursor @ 0          [782 padded i32, stride 16] -> 50,176
//   bar     @ 50,176     [1 i32]  (memset covers gcursor+bar: 51,200)
//   packed  @ 51,200     [782*1344 i32 = 4,204,032] -> 4,255,232
//   feat8   @ 4,255,232  [50001*128 u8; row 50000 = zeros] -> 10,655,360
//   Wc16    @ 10,655,360 [32768 bf16] -> 10,720,896
//   biasc   @ 10,720,896 [512] -> 10,721,408
#define OFF_GCURSOR 0ull
#define OFF_BAR     50176ull
#define OFF_PACKED  51200ull
#define OFF_FEAT8   4255232ull
#define OFF_WC16    10655360ull
#define OFF_BIASC   10720896ull

__device__ __forceinline__ float fp8tof_sw(unsigned char b) {
    __hip_fp8_e4m3 t; t.__x = b;
    return (float)t;
}

// One kernel, two phases split by a device-wide software barrier.
// Residency guarantee (required for the barrier): 512 thr, LDS 37.6KB -> 4
// blocks/CU; __launch_bounds__(512,8) caps VGPR at 64 (hard); grid 782 <= 1024.
__global__ __launch_bounds__(512, 8)
void mega_kernel(const int* __restrict__ src, const int* __restrict__ dst,
                 int* __restrict__ gcursor, int* __restrict__ bar,
                 int* __restrict__ packed,
                 const float* __restrict__ feat, unsigned char* __restrict__ feat8,
                 const float* __restrict__ Ws, const float* __restrict__ Wn,
                 const float* __restrict__ b_self, const float* __restrict__ bias,
                 __bf16* __restrict__ Wc16, float* __restrict__ biasc,
                 float* __restrict__ out, int n) {
    __shared__ __align__(16) char smem[64 * 264 * 2];   // 33,792 B: lh/pk/At/Ct
    __shared__ unsigned short srt[SRTN];                // 3,072 B
    __shared__ int cnt[64];
    __shared__ int loff[64];
    __shared__ int degs[64];
    const int tid = threadIdx.x;
    const int b = blockIdx.x;
    const int node0 = b * 64;

    // ================= Phase A =================
    // A1: own 64-row feat tile: f32 -> bf16 kept in REGISTERS across the
    // barrier (no feat16 round-trip) + fp8 row write for everyone's gather.
    const int srow = tid >> 3;
    const int scol = (tid & 7) * 16;          // 16 f32 elems per thread
    const int snn = node0 + srow;
    bf16x8 st0 = {}, st1 = {};
    if (snn < N_NODES) {
        const float* fp = feat + (size_t)snn * D + scol;
        float4 f0 = *(const float4*)(fp);
        float4 f1 = *(const float4*)(fp + 4);
        float4 f2 = *(const float4*)(fp + 8);
        float4 f3 = *(const float4*)(fp + 12);
        st0[0]=(__bf16)f0.x; st0[1]=(__bf16)f0.y; st0[2]=(__bf16)f0.z; st0[3]=(__bf16)f0.w;
        st0[4]=(__bf16)f1.x; st0[5]=(__bf16)f1.y; st0[6]=(__bf16)f1.z; st0[7]=(__bf16)f1.w;
        st1[0]=(__bf16)f2.x; st1[1]=(__bf16)f2.y; st1[2]=(__bf16)f2.z; st1[3]=(__bf16)f2.w;
        st1[4]=(__bf16)f3.x; st1[5]=(__bf16)f3.y; st1[6]=(__bf16)f3.z; st1[7]=(__bf16)f3.w;
#ifdef HW_FP8
        int q0 = __builtin_amdgcn_cvt_pk_fp8_f32(f0.x, f0.y, 0, false);
        q0     = __builtin_amdgcn_cvt_pk_fp8_f32(f0.z, f0.w, q0, true);
        int q1 = __builtin_amdgcn_cvt_pk_fp8_f32(f1.x, f1.y, 0, false);
        q1     = __builtin_amdgcn_cvt_pk_fp8_f32(f1.z, f1.w, q1, true);
        int q2 = __builtin_amdgcn_cvt_pk_fp8_f32(f2.x, f2.y, 0, false);
        q2     = __builtin_amdgcn_cvt_pk_fp8_f32(f2.z, f2.w, q2, true);
        int q3 = __builtin_amdgcn_cvt_pk_fp8_f32(f3.x, f3.y, 0, false);
        q3     = __builtin_amdgcn_cvt_pk_fp8_f32(f3.z, f3.w, q3, true);
        uint4 qq; qq.x=(unsigned)q0; qq.y=(unsigned)q1; qq.z=(unsigned)q2; qq.w=(unsigned)q3;
        *(uint4*)(feat8 + (size_t)snn * D + scol) = qq;
#else
        float fv[16] = {f0.x,f0.y,f0.z,f0.w, f1.x,f1.y,f1.z,f1.w,
                        f2.x,f2.y,f2.z,f2.w, f3.x,f3.y,f3.z,f3.w};
        union { unsigned char c[16]; uint4 u; } q;
        #pragma unroll
        for (int j = 0; j < 16; ++j) { __hip_fp8_e4m3 e(fv[j]); q.c[j] = e.__x; }
        *(uint4*)(feat8 + (size_t)snn * D + scol) = q.u;
#endif
    }

    // A2: weight/bias/zero-row extras on low block ids (done before barrier).
    if (b < 16) {
        int idx = b * 512 + tid;              // [0, 8192) float4 items
        int col = idx >> 6;
        int kq  = (idx & 63) * 4;
        const float* srcp = (kq < D) ? (Ws + (size_t)col * D + kq)
                                     : (Wn + (size_t)col * D + (kq - D));
        float4 f = *(const float4*)srcp;
        bf16x4 t;
        t[0]=(__bf16)f.x; t[1]=(__bf16)f.y; t[2]=(__bf16)f.z; t[3]=(__bf16)f.w;
        *(bf16x4*)(Wc16 + (size_t)col * 256 + kq) = t;
    } else if (b == 16) {
        if (tid < D) biasc[tid] = b_self[tid] + bias[tid];
        else if (tid < D + 32)   // fp8 zero row (index N_NODES)
            ((unsigned*)(feat8 + (size_t)N_NODES * D))[tid - 128] = 0u;
    }

    // A3: edge bucket scatter (block-aggregated cursors, coalesced runs).
    {
        int* lh = (int*)smem;
        int* lbase = lh + NBUK;
        for (int i = tid; i < NBUK; i += 512) lh[i] = 0;
        __syncthreads();
        const int e0 = b * EPB;
        int ea = e0 + tid, eb = e0 + 512 + tid;
        int d0 = -1, s0 = 0, d1 = -1, s1 = 0;
        if (ea < n) { d0 = dst[ea]; s0 = src[ea]; }
        if (eb < n) { d1 = dst[eb]; s1 = src[eb]; }
        if (d0 >= 0) atomicAdd(&lh[d0 >> 6], 1);
        if (d1 >= 0) atomicAdd(&lh[d1 >> 6], 1);
        __syncthreads();
        for (int i = tid; i < NBUK; i += 512) {
            int c = lh[i];
            lbase[i] = c ? atomicAdd(&gcursor[i * CURS], c) : 0;
            lh[i] = 0;                        // reuse as rank cursor
        }
        __syncthreads();
        if (d0 >= 0) {
            int bk = d0 >> 6;
            int r = atomicAdd(&lh[bk], 1);
            int pos = lbase[bk] + r;
            if (pos < CAPB) packed[(size_t)bk * CAPB + pos] = ((d0 & 63) << 16) | s0;
        }
        if (d1 >= 0) {
            int bk = d1 >> 6;
            int r = atomicAdd(&lh[bk], 1);
            int pos = lbase[bk] + r;
            if (pos < CAPB) packed[(size_t)bk * CAPB + pos] = ((d1 & 63) << 16) | s1;
        }
    }
    __syncthreads();

    // ============ device-wide barrier (agent-scope acq/rel) ============
    if (tid == 0) {
        __hip_atomic_fetch_add(bar, 1, __ATOMIC_ACQ_REL, __HIP_MEMORY_SCOPE_AGENT);
        while (__hip_atomic_load(bar, __ATOMIC_ACQUIRE, __HIP_MEMORY_SCOPE_AGENT) < NBUK)
            __builtin_amdgcn_s_sleep(8);
    }
    __syncthreads();

    // ================= Phase B =================
    __bf16 (*At)[264] = (__bf16 (*)[264])smem;
    int* pk = (int*)smem;
    const int ecnt = min(gcursor[b * CURS], CAPB);

    if (tid < 64) cnt[tid] = 0;
    for (int i = tid; i < ecnt; i += 512) pk[i] = packed[(size_t)b * CAPB + i];
    __syncthreads();

    // histogram over 64 local nodes
    for (int i = tid; i < ecnt; i += 512) atomicAdd(&cnt[pk[i] >> 16], 1);
    __syncthreads();
    // exclusive scan of pad-to-4 lengths, wave 0 (64 lanes = 64 nodes)
    if (tid < 64) {
        int c = cnt[tid];
        int cp = (c + 3) & ~3;
        int v = cp;
        #pragma unroll
        for (int o = 1; o < 64; o <<= 1) {
            int u = __shfl_up(v, o);
            if (tid >= o) v += u;
        }
        loff[tid] = v - cp;
        degs[tid] = c;
        cnt[tid] = 0;                  // reuse as rank cursor
    }
    __syncthreads();
    // rank-scatter into per-node u16 lists
    for (int i = tid; i < ecnt; i += 512) {
        int p = pk[i];
        int l = p >> 16;
        int r = atomicAdd(&cnt[l], 1);
        srt[loff[l] + r] = (unsigned short)p;     // low 16 bits = src id
    }
    if (tid < 64) {
        int c = degs[tid];
        int cp = (c + 3) & ~3;
        int base0 = loff[tid];
        for (int j = c; j < cp; ++j) srt[base0 + j] = (unsigned short)N_NODES;
    }
    __syncthreads();                   // pk dead from here on

    // stage self rows into At from registers (overlays pk region — safe now)
    *(bf16x8*)&At[srow][scol] = st0;
    *(bf16x8*)&At[srow][scol + 8] = st1;

    // gather-mean from fp8, 16 half-waves x 4 nodes, 4-deep batches.
    {
        const int hw = tid >> 5;          // 0..15
        const int lane = tid & 31;
        const unsigned int* g8 = (const unsigned int*)feat8;
        #pragma unroll
        for (int t = 0; t < 4; ++t) {
            int i = hw + t * 16;
            int dg = degs[i];
            int dgp = (dg + 3) & ~3;
            const int base0 = loff[i];
            float a0 = 0.f, a1 = 0.f, a2 = 0.f, a3 = 0.f;
            for (int j = 0; j < dgp; j += 4) {
                unsigned int w[4];
                #pragma unroll
                for (int q = 0; q < 4; ++q) {
                    int s = srt[base0 + j + q];
                    w[q] = g8[(size_t)s * 32 + lane];
                }
                #pragma unroll
                for (int q = 0; q < 4; ++q) {
#ifdef HW_FP8
                    f32x2 lo = __builtin_amdgcn_cvt_pk_f32_fp8((int)w[q], false);
                    f32x2 hi = __builtin_amdgcn_cvt_pk_f32_fp8((int)w[q], true);
                    a0 += lo[0]; a1 += lo[1]; a2 += hi[0]; a3 += hi[1];
#else
                    a0 += fp8tof_sw(w[q] & 0xFF);
                    a1 += fp8tof_sw((w[q] >> 8) & 0xFF);
                    a2 += fp8tof_sw((w[q] >> 16) & 0xFF);
                    a3 += fp8tof_sw(w[q] >> 24);
#endif
                }
            }
            float sc = dg > 0 ? 1.0f / (float)dg : 0.f;   // DGL mean: deg==0 -> 0
            bf16x4 hv;
            hv[0] = (__bf16)(a0 * sc); hv[1] = (__bf16)(a1 * sc);
            hv[2] = (__bf16)(a2 * sc); hv[3] = (__bf16)(a3 * sc);
            *(bf16x4*)&At[i][128 + lane * 4] = hv;
        }
    }
    __syncthreads();

    // K=256 MFMA GEMM. Wave w (0..7): rows (w&1)*32..+32, cols (w>>1)*32..+32.
    const int wv = tid >> 6;
    const int lane = tid & 63;
    const int m = lane & 15;
    const int quad = lane >> 4;
    const int r0 = (wv & 1) * 32;
    const int c0 = (wv >> 1) * 32;

    f32x4 acc[2][2] = {};
    #pragma unroll
    for (int k0 = 0; k0 < 256; k0 += 32) {
        const int kk = k0 + quad * 8;
        bf16x8 a0 = *(const bf16x8*)&At[r0 + m][kk];
        bf16x8 a1 = *(const bf16x8*)&At[r0 + 16 + m][kk];
        #pragma unroll
        for (int ct = 0; ct < 2; ++ct) {
            int col = c0 + ct * 16 + m;
            bf16x8 bb = *(const bf16x8*)(Wc16 + (size_t)col * 256 + kk);
            acc[0][ct] = __builtin_amdgcn_mfma_f32_16x16x32_bf16(a0, bb, acc[0][ct], 0, 0, 0);
            acc[1][ct] = __builtin_amdgcn_mfma_f32_16x16x32_bf16(a1, bb, acc[1][ct], 0, 0, 0);
        }
    }
    __syncthreads();   // done reading At

    // epilogue: transpose-store via Ct overlay (stride 132 f32), float4 stores.
    float* Ct = (float*)smem;
    #pragma unroll
    for (int rt = 0; rt < 2; ++rt) {
        #pragma unroll
        for (int ct = 0; ct < 2; ++ct) {
            int ccol = c0 + ct * 16 + m;
            int crow = r0 + rt * 16 + quad * 4;
            #pragma unroll
            for (int r = 0; r < 4; ++r)
                Ct[(crow + r) * 132 + ccol] = acc[rt][ct][r];
        }
    }
    __syncthreads();
    for (int idx = tid; idx < 64 * 32; idx += 512) {
        int row = idx >> 5;
        int c4 = (idx & 31) * 4;
        int nn = node0 + row;
        if (nn < N_NODES) {
            float4 v = *(float4*)&Ct[row * 132 + c4];
            float4 bb = *(const float4*)(biasc + c4);
            v.x += bb.x; v.y += bb.y; v.z += bb.z; v.w += bb.w;
            *(float4*)&out[(size_t)nn * D + c4] = v;
        }
    }
}

extern "C" void kernel_launch(void* const* d_in, const int* in_sizes, int n_in,
                              void* d_out, int out_size, void* d_ws, size_t ws_size,
                              hipStream_t stream) {
    const float* feat    = (const float*)d_in[0];
    const int*   src     = (const int*)d_in[1];
    const int*   dst     = (const int*)d_in[2];
    const float* W_self  = (const float*)d_in[3];
    const float* b_self  = (const float*)d_in[4];
    const float* W_neigh = (const float*)d_in[5];
    const float* bias    = (const float*)d_in[6];
    float* out = (float*)d_out;
    char*  ws  = (char*)d_ws;

    int* gcursor = (int*)(ws + OFF_GCURSOR);
    int* bar     = (int*)(ws + OFF_BAR);
    int* packed  = (int*)(ws + OFF_PACKED);
    unsigned char* feat8 = (unsigned char*)(ws + OFF_FEAT8);
    __bf16* Wc16  = (__bf16*)(ws + OFF_WC16);
    float*  biasc = (float*)(ws + OFF_BIASC);
    const int n_edges = in_sizes[1];

    hipMemsetAsync(ws, 0, 51200, stream);     // gcursor + bar
    mega_kernel<<<dim3(NBUK), 512, 0, stream>>>(
        src, dst, gcursor, bar, packed, feat, feat8,
        W_self, W_neigh, b_self, bias, Wc16, biasc, out, n_edges);
}

// Round 7
// 136.199 us; speedup vs baseline: 1.9486x; 1.9486x over previous
//
#include <hip/hip_runtime.h>
#include <hip/hip_fp8.h>

#define N_NODES 50000
#define N_EDGES 800000
#define D 128
#define NBUK 782         // 64-node dst buckets: ceil(50000/64)
#define CAPB 1344        // per-bucket edge cap in fused (mean ~1023, +10 sigma)
#define SRTN (CAPB + 64*7)   // 1792 ints: pad-to-8 worst case
#define EPB 2048
#define SCAT_BLOCKS 391  // 391*2048 = 800768 >= 800000
#define FEAT_BLOCKS 3125 // 3125*256*8 = 6.4M = 50000*128
#define W_BLOCKS 32
#define CAPC 16          // slots per (bucket, scatter-block) cell = one 64B line

typedef __bf16 bf16x8 __attribute__((ext_vector_type(8)));
typedef __bf16 bf16x4 __attribute__((ext_vector_type(4)));
typedef float  f32x4  __attribute__((ext_vector_type(4)));
typedef float  f32x2  __attribute__((ext_vector_type(2)));

#if defined(__has_builtin)
#if __has_builtin(__builtin_amdgcn_cvt_pk_f32_fp8) && __has_builtin(__builtin_amdgcn_cvt_pk_fp8_f32)
#define HW_FP8 1
#endif
#endif

// ws layout (bytes), NO memset needed (stripe fully written each call):
//   packed @ 0          [782*391*16 i32 = 4,892,192 i32 = 19,568,768 B]
//   feat8  @ 19,568,768 [50001*128 u8 = 6,400,128; row 50000 = zeros] -> 25,968,896
//   Wc16   @ 25,968,896 [32768 bf16 = 65,536] -> 26,034,432
//   biasc  @ 26,034,432 [512] -> 26,034,944
// (R6 bug: OFF_FEAT8 was 19,567,104 < packed end -> stripe tail stomped fp8
//  rows 0..12 with 0xFF = e4m3 NaN. Offsets now audited: 305,762 cells * 64 B.)
#define OFF_PACKED 0ull
#define OFF_FEAT8  19568768ull
#define OFF_WC16   25968896ull
#define OFF_BIASC  26034432ull

__device__ __forceinline__ float fp8tof_sw(unsigned char b) {
    __hip_fp8_e4m3 t; t.__x = b;
    return (float)t;
}

// ---- prep: deterministic stripe scatter (ZERO global atomics)
//            || feat->fp8 || weights || bias -----------------------------
__global__ __launch_bounds__(256)
void prep_kernel(const int* __restrict__ src, const int* __restrict__ dst,
                 int* __restrict__ packed,
                 const float* __restrict__ feat, unsigned char* __restrict__ feat8,
                 const float* __restrict__ Ws, const float* __restrict__ Wn,
                 const float* __restrict__ b_self, const float* __restrict__ bias,
                 __bf16* __restrict__ Wc16, float* __restrict__ biasc, int n) {
    const int tid = threadIdx.x;
    const int bid = blockIdx.x;
    if (bid < SCAT_BLOCKS) {
        __shared__ int hist[NBUK];     // histogram, then rank cursor
        __shared__ int boff[NBUK];     // exclusive offsets into srtL
        __shared__ int srtL[EPB];      // block's edges sorted by bucket
        __shared__ int wtot[4];
        const int e0 = bid * EPB;
        int d[8], s[8];
        for (int i = tid; i < NBUK; i += 256) hist[i] = 0;
        __syncthreads();
        // pass A: histogram; keep (d,s) in registers
        #pragma unroll
        for (int j = 0; j < 8; ++j) {
            int e = e0 + j * 256 + tid;
            bool ok = e < n;
            d[j] = ok ? dst[e] : -1;
            s[j] = ok ? src[e] : 0;
            if (ok) atomicAdd(&hist[d[j] >> 6], 1);
        }
        __syncthreads();
        // block-wide exclusive scan over 782 buckets (4 buckets/thread)
        {
            const int lane = tid & 63;
            const int wv = tid >> 6;
            const int b4 = tid * 4;
            int h0 = (b4 + 0 < NBUK) ? hist[b4 + 0] : 0;
            int h1 = (b4 + 1 < NBUK) ? hist[b4 + 1] : 0;
            int h2 = (b4 + 2 < NBUK) ? hist[b4 + 2] : 0;
            int h3 = (b4 + 3 < NBUK) ? hist[b4 + 3] : 0;
            int sm = h0 + h1 + h2 + h3;
            int v = sm;
            #pragma unroll
            for (int o = 1; o < 64; o <<= 1) {
                int u = __shfl_up(v, o);
                if (lane >= o) v += u;
            }
            if (lane == 63) wtot[wv] = v;
            __syncthreads();
            if (tid == 0) {
                int r = 0;
                #pragma unroll
                for (int j = 0; j < 4; ++j) { int t = wtot[j]; wtot[j] = r; r += t; }
            }
            __syncthreads();
            int ex = wtot[wv] + v - sm;       // exclusive prefix of this group
            if (b4 + 0 < NBUK) { boff[b4 + 0] = ex;                hist[b4 + 0] = 0; }
            if (b4 + 1 < NBUK) { boff[b4 + 1] = ex + h0;           hist[b4 + 1] = 0; }
            if (b4 + 2 < NBUK) { boff[b4 + 2] = ex + h0 + h1;      hist[b4 + 2] = 0; }
            if (b4 + 3 < NBUK) { boff[b4 + 3] = ex + h0 + h1 + h2; hist[b4 + 3] = 0; }
        }
        __syncthreads();
        // rank-scatter into bucket-sorted LDS list
        #pragma unroll
        for (int j = 0; j < 8; ++j) {
            if (d[j] >= 0) {
                int bk = d[j] >> 6;
                int r = atomicAdd(&hist[bk], 1);
                srtL[boff[bk] + r] = ((d[j] & 63) << 16) | s[j];
            }
        }
        __syncthreads();
        // write-out: one 64B cell per bucket, fully written (sentinel pad)
        for (int idx = tid; idx < NBUK * 4; idx += 256) {
            int bk = idx >> 2;
            int q4 = (idx & 3) * 4;
            int off = boff[bk];
            int c = hist[bk];
            int4 v;
            v.x = (q4 + 0 < c) ? srtL[off + q4 + 0] : -1;
            v.y = (q4 + 1 < c) ? srtL[off + q4 + 1] : -1;
            v.z = (q4 + 2 < c) ? srtL[off + q4 + 2] : -1;
            v.w = (q4 + 3 < c) ? srtL[off + q4 + 3] : -1;
            *(int4*)&packed[((size_t)bk * SCAT_BLOCKS + bid) * CAPC + q4] = v;
        }
    } else if (bid < SCAT_BLOCKS + FEAT_BLOCKS) {
        size_t i = ((size_t)(bid - SCAT_BLOCKS) * 256 + tid) * 8;
        float4 f0 = *(const float4*)(feat + i);
        float4 f1 = *(const float4*)(feat + i + 4);
#ifdef HW_FP8
        int q0 = __builtin_amdgcn_cvt_pk_fp8_f32(f0.x, f0.y, 0, false);
        q0     = __builtin_amdgcn_cvt_pk_fp8_f32(f0.z, f0.w, q0, true);
        int q1 = __builtin_amdgcn_cvt_pk_fp8_f32(f1.x, f1.y, 0, false);
        q1     = __builtin_amdgcn_cvt_pk_fp8_f32(f1.z, f1.w, q1, true);
        uint2 qq; qq.x = (unsigned)q0; qq.y = (unsigned)q1;
        *(uint2*)(feat8 + i) = qq;
#else
        float fv[8] = {f0.x, f0.y, f0.z, f0.w, f1.x, f1.y, f1.z, f1.w};
        union { unsigned char b[8]; unsigned long long u; } q;
        #pragma unroll
        for (int j = 0; j < 8; ++j) { __hip_fp8_e4m3 e(fv[j]); q.b[j] = e.__x; }
        *(unsigned long long*)(feat8 + i) = q.u;
#endif
    } else if (bid < SCAT_BLOCKS + FEAT_BLOCKS + W_BLOCKS) {
        int idx = (bid - SCAT_BLOCKS - FEAT_BLOCKS) * 256 + tid;   // < 8192
        int col = idx >> 6;
        int kq  = (idx & 63) * 4;
        const float* srcp = (kq < D) ? (Ws + (size_t)col * D + kq)
                                     : (Wn + (size_t)col * D + (kq - D));
        float4 f = *(const float4*)srcp;
        bf16x4 t;
        t[0]=(__bf16)f.x; t[1]=(__bf16)f.y; t[2]=(__bf16)f.z; t[3]=(__bf16)f.w;
        *(bf16x4*)(Wc16 + (size_t)col * 256 + kq) = t;
    } else {
        if (tid < D) biasc[tid] = b_self[tid] + bias[tid];
        else if (tid < D + 32)   // fp8 zero row (index N_NODES)
            ((unsigned*)(feat8 + (size_t)N_NODES * D))[tid - 128] = 0u;
    }
}

// ---- fused: one block per 64-node bucket, 512 threads (proven R3 config).
// Stream stripe -> compact -> LDS sort -> stage self rows -> fp8 gather-mean
// -> K=256 MFMA GEMM -> bias + store.
__global__ __launch_bounds__(512)
void fused_kernel(const float* __restrict__ feat,
                  const unsigned char* __restrict__ feat8,
                  const int* __restrict__ packed,
                  const __bf16* __restrict__ Wc16,
                  const float* __restrict__ biasc,
                  float* __restrict__ out) {
    __shared__ __bf16 At[64][264];     // 33,792 B; Ct overlay in epilogue
    __shared__ int pk[CAPB];           // 5,376 B
    __shared__ int srt[SRTN];          // 7,168 B
    __shared__ int cnt[64];
    __shared__ int loff[64];
    __shared__ int degs[64];
    __shared__ int nv;
    const int tid = threadIdx.x;
    const int b = blockIdx.x;
    const int node0 = b * 64;

    if (tid == 0) nv = 0;
    if (tid < 64) cnt[tid] = 0;
    __syncthreads();

    // compact valid edges from this bucket's stripe row (391 cells, 25KB dense)
    {
        const int4* sp = (const int4*)(packed + (size_t)b * SCAT_BLOCKS * CAPC);
        for (int i = tid; i < SCAT_BLOCKS * 4; i += 512) {
            int4 v = sp[i];
            if (v.x != -1) { int p = atomicAdd(&nv, 1); if (p < CAPB) pk[p] = v.x; }
            if (v.y != -1) { int p = atomicAdd(&nv, 1); if (p < CAPB) pk[p] = v.y; }
            if (v.z != -1) { int p = atomicAdd(&nv, 1); if (p < CAPB) pk[p] = v.z; }
            if (v.w != -1) { int p = atomicAdd(&nv, 1); if (p < CAPB) pk[p] = v.w; }
        }
    }

    // Phase 1: self rows, convert f32->bf16 while staging (feat LLC/L2-warm).
    for (int idx = tid; idx < 1024; idx += 512) {
        int row = idx >> 4;
        int seg = (idx & 15) * 8;
        int nn = node0 + row;
        bf16x8 t = {};
        if (nn < N_NODES) {
            const float* fp = feat + (size_t)nn * D + seg;
            float4 f0 = *(const float4*)fp;
            float4 f1 = *(const float4*)(fp + 4);
            t[0]=(__bf16)f0.x; t[1]=(__bf16)f0.y; t[2]=(__bf16)f0.z; t[3]=(__bf16)f0.w;
            t[4]=(__bf16)f1.x; t[5]=(__bf16)f1.y; t[6]=(__bf16)f1.z; t[7]=(__bf16)f1.w;
        }
        *(bf16x8*)&At[row][seg] = t;
    }
    __syncthreads();
    const int ecnt = min(nv, CAPB);

    // Sort prologue: histogram over 64 local nodes
    for (int i = tid; i < ecnt; i += 512) atomicAdd(&cnt[pk[i] >> 16], 1);
    __syncthreads();
    // exclusive scan of pad-to-8 lengths, wave 0 (64 lanes = 64 nodes)
    if (tid < 64) {
        int c = cnt[tid];
        int cp = (c + 7) & ~7;
        int v = cp;
        #pragma unroll
        for (int o = 1; o < 64; o <<= 1) {
            int u = __shfl_up(v, o);
            if (tid >= o) v += u;
        }
        loff[tid] = v - cp;
        degs[tid] = c;
        cnt[tid] = 0;                  // reuse as rank cursor
    }
    __syncthreads();
    // rank-scatter into per-node lists + pad tails with zero row
    for (int i = tid; i < ecnt; i += 512) {
        int p = pk[i];
        int l = p >> 16;
        int r = atomicAdd(&cnt[l], 1);
        srt[loff[l] + r] = p & 0xFFFF;
    }
    if (tid < 64) {
        int c = degs[tid];
        int cp = (c + 7) & ~7;
        int base0 = loff[tid];
        for (int j = c; j < cp; ++j) srt[base0 + j] = N_NODES;
    }
    __syncthreads();

    // Phase 2: gather-mean from fp8, 16 half-waves x 4 nodes, 8-deep batches.
    {
        const int hw = tid >> 5;          // 0..15
        const int lane = tid & 31;
        const unsigned int* g8 = (const unsigned int*)feat8;
        #pragma unroll
        for (int t = 0; t < 4; ++t) {
            int i = hw + t * 16;
            int dg = degs[i];
            int dgp = (dg + 7) & ~7;
            const int base0 = loff[i];
            float a0 = 0.f, a1 = 0.f, a2 = 0.f, a3 = 0.f;
            for (int j = 0; j < dgp; j += 8) {
                int s[8]; unsigned int w[8];
                #pragma unroll
                for (int q = 0; q < 8; ++q) s[q] = srt[base0 + j + q];
                #pragma unroll
                for (int q = 0; q < 8; ++q)
                    w[q] = g8[(size_t)s[q] * 32 + lane];
                #pragma unroll
                for (int q = 0; q < 8; ++q) {
#ifdef HW_FP8
                    f32x2 lo = __builtin_amdgcn_cvt_pk_f32_fp8((int)w[q], false);
                    f32x2 hi = __builtin_amdgcn_cvt_pk_f32_fp8((int)w[q], true);
                    a0 += lo[0]; a1 += lo[1]; a2 += hi[0]; a3 += hi[1];
#else
                    a0 += fp8tof_sw(w[q] & 0xFF);
                    a1 += fp8tof_sw((w[q] >> 8) & 0xFF);
                    a2 += fp8tof_sw((w[q] >> 16) & 0xFF);
                    a3 += fp8tof_sw(w[q] >> 24);
#endif
                }
            }
            float sc = dg > 0 ? 1.0f / (float)dg : 0.f;   // DGL mean: deg==0 -> 0
            bf16x4 hv;
            hv[0] = (__bf16)(a0 * sc); hv[1] = (__bf16)(a1 * sc);
            hv[2] = (__bf16)(a2 * sc); hv[3] = (__bf16)(a3 * sc);
            *(bf16x4*)&At[i][128 + lane * 4] = hv;
        }
    }
    __syncthreads();

    // Phase 3: K=256 MFMA GEMM. Wave w (0..7): rows (w&1)*32..+32,
    // cols (w>>1)*32..+32.
    const int wv = tid >> 6;
    const int lane = tid & 63;
    const int m = lane & 15;
    const int quad = lane >> 4;
    const int r0 = (wv & 1) * 32;
    const int c0 = (wv >> 1) * 32;

    f32x4 acc[2][2] = {};
    #pragma unroll
    for (int k0 = 0; k0 < 256; k0 += 32) {
        const int kk = k0 + quad * 8;
        bf16x8 a0 = *(const bf16x8*)&At[r0 + m][kk];
        bf16x8 a1 = *(const bf16x8*)&At[r0 + 16 + m][kk];
        #pragma unroll
        for (int ct = 0; ct < 2; ++ct) {
            int col = c0 + ct * 16 + m;
            bf16x8 bb = *(const bf16x8*)(Wc16 + (size_t)col * 256 + kk);
            acc[0][ct] = __builtin_amdgcn_mfma_f32_16x16x32_bf16(a0, bb, acc[0][ct], 0, 0, 0);
            acc[1][ct] = __builtin_amdgcn_mfma_f32_16x16x32_bf16(a1, bb, acc[1][ct], 0, 0, 0);
        }
    }
    __syncthreads();   // done reading At

    // Phase 4: transpose-store via Ct overlay (stride 132 f32), float4 stores.
    float* Ct = (float*)&At[0][0];
    #pragma unroll
    for (int rt = 0; rt < 2; ++rt) {
        #pragma unroll
        for (int ct = 0; ct < 2; ++ct) {
            int ccol = c0 + ct * 16 + m;
            int crow = r0 + rt * 16 + quad * 4;
            #pragma unroll
            for (int r = 0; r < 4; ++r)
                Ct[(crow + r) * 132 + ccol] = acc[rt][ct][r];
        }
    }
    __syncthreads();
    for (int idx = tid; idx < 64 * 32; idx += 512) {
        int row = idx >> 5;
        int c4 = (idx & 31) * 4;
        int nn = node0 + row;
        if (nn < N_NODES) {
            float4 v = *(float4*)&Ct[row * 132 + c4];
            float4 bb = *(const float4*)(biasc + c4);
            v.x += bb.x; v.y += bb.y; v.z += bb.z; v.w += bb.w;
            *(float4*)&out[(size_t)nn * D + c4] = v;
        }
    }
}

extern "C" void kernel_launch(void* const* d_in, const int* in_sizes, int n_in,
                              void* d_out, int out_size, void* d_ws, size_t ws_size,
                              hipStream_t stream) {
    const float* feat    = (const float*)d_in[0];
    const int*   src     = (const int*)d_in[1];
    const int*   dst     = (const int*)d_in[2];
    const float* W_self  = (const float*)d_in[3];
    const float* b_self  = (const float*)d_in[4];
    const float* W_neigh = (const float*)d_in[5];
    const float* bias    = (const float*)d_in[6];
    float* out = (float*)d_out;
    char*  ws  = (char*)d_ws;

    int* packed  = (int*)(ws + OFF_PACKED);
    unsigned char* feat8 = (unsigned char*)(ws + OFF_FEAT8);
    __bf16* Wc16  = (__bf16*)(ws + OFF_WC16);
    float*  biasc = (float*)(ws + OFF_BIASC);
    const int n_edges = in_sizes[1];

    prep_kernel<<<dim3(SCAT_BLOCKS + FEAT_BLOCKS + W_BLOCKS + 1), 256, 0, stream>>>(
        src, dst, packed, feat, feat8, W_self, W_neigh, b_self, bias,
        Wc16, biasc, n_edges);
    fused_kernel<<<dim3(NBUK), 512, 0, stream>>>(
        feat, feat8, packed, Wc16, biasc, out);
}

// Round 8
// 131.002 us; speedup vs baseline: 2.0259x; 1.0397x over previous
//
#include <hip/hip_runtime.h>
#include <hip/hip_fp8.h>

#define N_NODES 50000
#define N_EDGES 800000
#define D 128
#define NBUK 782         // 64-node dst buckets: ceil(50000/64)
#define CAPB 1344        // per-bucket edge cap in fused (mean ~1023, +10 sigma)
#define SRTN (CAPB + 64*7)   // 1792 u16: pad-to-8 worst case
#define EPB 2048
#define SCAT_BLOCKS 391  // 391*2048 = 800768 >= 800000
#define FEAT_BLOCKS 3125 // 3125*256*8 = 6.4M = 50000*128
#define W_BLOCKS 32
#define CAPC 16          // slots per (bucket, scatter-block) cell = one 64B line

typedef __bf16 bf16x8 __attribute__((ext_vector_type(8)));
typedef __bf16 bf16x4 __attribute__((ext_vector_type(4)));
typedef float  f32x4  __attribute__((ext_vector_type(4)));
typedef float  f32x2  __attribute__((ext_vector_type(2)));

#if defined(__has_builtin)
#if __has_builtin(__builtin_amdgcn_cvt_pk_f32_fp8) && __has_builtin(__builtin_amdgcn_cvt_pk_fp8_f32)
#define HW_FP8 1
#endif
#endif

// ws layout (bytes), NO memset needed (stripe fully written each call):
//   packed @ 0          [782*391*16 i32 = 4,892,192 i32 = 19,568,768 B]
//   feat8  @ 19,568,768 [50001*128 u8 = 6,400,128; row 50000 = zeros] -> 25,968,896
//   Wc16   @ 25,968,896 [32768 bf16 = 65,536] -> 26,034,432
//   biasc  @ 26,034,432 [512] -> 26,034,944
#define OFF_PACKED 0ull
#define OFF_FEAT8  19568768ull
#define OFF_WC16   25968896ull
#define OFF_BIASC  26034432ull

__device__ __forceinline__ float fp8tof_sw(unsigned char b) {
    __hip_fp8_e4m3 t; t.__x = b;
    return (float)t;
}

// ---- prep: deterministic stripe scatter (ZERO global atomics)
//            || feat->fp8 || weights || bias -----------------------------
__global__ __launch_bounds__(256)
void prep_kernel(const int* __restrict__ src, const int* __restrict__ dst,
                 int* __restrict__ packed,
                 const float* __restrict__ feat, unsigned char* __restrict__ feat8,
                 const float* __restrict__ Ws, const float* __restrict__ Wn,
                 const float* __restrict__ b_self, const float* __restrict__ bias,
                 __bf16* __restrict__ Wc16, float* __restrict__ biasc, int n) {
    const int tid = threadIdx.x;
    const int bid = blockIdx.x;
    if (bid < SCAT_BLOCKS) {
        __shared__ int hist[NBUK];     // histogram, then rank cursor
        __shared__ int boff[NBUK];     // exclusive offsets into srtL
        __shared__ int srtL[EPB];      // block's edges sorted by bucket
        __shared__ int wtot[4];
        const int e0 = bid * EPB;
        int d[8], s[8];
        for (int i = tid; i < NBUK; i += 256) hist[i] = 0;
        __syncthreads();
        // pass A: histogram; keep (d,s) in registers
        #pragma unroll
        for (int j = 0; j < 8; ++j) {
            int e = e0 + j * 256 + tid;
            bool ok = e < n;
            d[j] = ok ? dst[e] : -1;
            s[j] = ok ? src[e] : 0;
            if (ok) atomicAdd(&hist[d[j] >> 6], 1);
        }
        __syncthreads();
        // block-wide exclusive scan over 782 buckets (4 buckets/thread)
        {
            const int lane = tid & 63;
            const int wv = tid >> 6;
            const int b4 = tid * 4;
            int h0 = (b4 + 0 < NBUK) ? hist[b4 + 0] : 0;
            int h1 = (b4 + 1 < NBUK) ? hist[b4 + 1] : 0;
            int h2 = (b4 + 2 < NBUK) ? hist[b4 + 2] : 0;
            int h3 = (b4 + 3 < NBUK) ? hist[b4 + 3] : 0;
            int sm = h0 + h1 + h2 + h3;
            int v = sm;
            #pragma unroll
            for (int o = 1; o < 64; o <<= 1) {
                int u = __shfl_up(v, o);
                if (lane >= o) v += u;
            }
            if (lane == 63) wtot[wv] = v;
            __syncthreads();
            if (tid == 0) {
                int r = 0;
                #pragma unroll
                for (int j = 0; j < 4; ++j) { int t = wtot[j]; wtot[j] = r; r += t; }
            }
            __syncthreads();
            int ex = wtot[wv] + v - sm;       // exclusive prefix of this group
            if (b4 + 0 < NBUK) { boff[b4 + 0] = ex;                hist[b4 + 0] = 0; }
            if (b4 + 1 < NBUK) { boff[b4 + 1] = ex + h0;           hist[b4 + 1] = 0; }
            if (b4 + 2 < NBUK) { boff[b4 + 2] = ex + h0 + h1;      hist[b4 + 2] = 0; }
            if (b4 + 3 < NBUK) { boff[b4 + 3] = ex + h0 + h1 + h2; hist[b4 + 3] = 0; }
        }
        __syncthreads();
        // rank-scatter into bucket-sorted LDS list
        #pragma unroll
        for (int j = 0; j < 8; ++j) {
            if (d[j] >= 0) {
                int bk = d[j] >> 6;
                int r = atomicAdd(&hist[bk], 1);
                srtL[boff[bk] + r] = ((d[j] & 63) << 16) | s[j];
            }
        }
        __syncthreads();
        // write-out: one 64B cell per bucket, fully written (sentinel pad)
        for (int idx = tid; idx < NBUK * 4; idx += 256) {
            int bk = idx >> 2;
            int q4 = (idx & 3) * 4;
            int off = boff[bk];
            int c = hist[bk];
            int4 v;
            v.x = (q4 + 0 < c) ? srtL[off + q4 + 0] : -1;
            v.y = (q4 + 1 < c) ? srtL[off + q4 + 1] : -1;
            v.z = (q4 + 2 < c) ? srtL[off + q4 + 2] : -1;
            v.w = (q4 + 3 < c) ? srtL[off + q4 + 3] : -1;
            *(int4*)&packed[((size_t)bk * SCAT_BLOCKS + bid) * CAPC + q4] = v;
        }
    } else if (bid < SCAT_BLOCKS + FEAT_BLOCKS) {
        size_t i = ((size_t)(bid - SCAT_BLOCKS) * 256 + tid) * 8;
        float4 f0 = *(const float4*)(feat + i);
        float4 f1 = *(const float4*)(feat + i + 4);
#ifdef HW_FP8
        int q0 = __builtin_amdgcn_cvt_pk_fp8_f32(f0.x, f0.y, 0, false);
        q0     = __builtin_amdgcn_cvt_pk_fp8_f32(f0.z, f0.w, q0, true);
        int q1 = __builtin_amdgcn_cvt_pk_fp8_f32(f1.x, f1.y, 0, false);
        q1     = __builtin_amdgcn_cvt_pk_fp8_f32(f1.z, f1.w, q1, true);
        uint2 qq; qq.x = (unsigned)q0; qq.y = (unsigned)q1;
        *(uint2*)(feat8 + i) = qq;
#else
        float fv[8] = {f0.x, f0.y, f0.z, f0.w, f1.x, f1.y, f1.z, f1.w};
        union { unsigned char b[8]; unsigned long long u; } q;
        #pragma unroll
        for (int j = 0; j < 8; ++j) { __hip_fp8_e4m3 e(fv[j]); q.b[j] = e.__x; }
        *(unsigned long long*)(feat8 + i) = q.u;
#endif
    } else if (bid < SCAT_BLOCKS + FEAT_BLOCKS + W_BLOCKS) {
        int idx = (bid - SCAT_BLOCKS - FEAT_BLOCKS) * 256 + tid;   // < 8192
        int col = idx >> 6;
        int kq  = (idx & 63) * 4;
        const float* srcp = (kq < D) ? (Ws + (size_t)col * D + kq)
                                     : (Wn + (size_t)col * D + (kq - D));
        float4 f = *(const float4*)srcp;
        bf16x4 t;
        t[0]=(__bf16)f.x; t[1]=(__bf16)f.y; t[2]=(__bf16)f.z; t[3]=(__bf16)f.w;
        *(bf16x4*)(Wc16 + (size_t)col * 256 + kq) = t;
    } else {
        if (tid < D) biasc[tid] = b_self[tid] + bias[tid];
        else if (tid < D + 32)   // fp8 zero row (index N_NODES)
            ((unsigned*)(feat8 + (size_t)N_NODES * D))[tid - 128] = 0u;
    }
}

// ---- fused: one block per 64-node bucket, 512 threads, 4 blocks/CU.
// LDS 38.2KB: pk overlays At (self rows ride in registers across the sort,
// R5-validated overlay), srt is u16. Wave-aggregated compact: one nv atomic
// per wave per round + fused histogram.
__global__ __launch_bounds__(512)
void fused_kernel(const float* __restrict__ feat,
                  const unsigned char* __restrict__ feat8,
                  const int* __restrict__ packed,
                  const __bf16* __restrict__ Wc16,
                  const float* __restrict__ biasc,
                  float* __restrict__ out) {
    __shared__ __align__(16) char smem[64 * 264 * 2];   // 33,792 B: pk / At / Ct
    __shared__ unsigned short srt[SRTN];                // 3,584 B
    __shared__ int cnt[64];
    __shared__ int loff[64];
    __shared__ int degs[64];
    __shared__ int nv;
    __bf16 (*At)[264] = (__bf16 (*)[264])smem;
    int* pk = (int*)smem;
    const int tid = threadIdx.x;
    const int b = blockIdx.x;
    const int node0 = b * 64;
    const int lane64 = tid & 63;

    // T14: issue self-row f32 loads NOW; convert to bf16 regs; consume
    // after the sort (HBM latency hides under compact/sort).
    const int srow = tid >> 3;
    const int scol = (tid & 7) * 16;
    const int snn = node0 + srow;
    bf16x8 st0 = {}, st1 = {};
    if (snn < N_NODES) {
        const float* fp = feat + (size_t)snn * D + scol;
        float4 f0 = *(const float4*)(fp);
        float4 f1 = *(const float4*)(fp + 4);
        float4 f2 = *(const float4*)(fp + 8);
        float4 f3 = *(const float4*)(fp + 12);
        st0[0]=(__bf16)f0.x; st0[1]=(__bf16)f0.y; st0[2]=(__bf16)f0.z; st0[3]=(__bf16)f0.w;
        st0[4]=(__bf16)f1.x; st0[5]=(__bf16)f1.y; st0[6]=(__bf16)f1.z; st0[7]=(__bf16)f1.w;
        st1[0]=(__bf16)f2.x; st1[1]=(__bf16)f2.y; st1[2]=(__bf16)f2.z; st1[3]=(__bf16)f2.w;
        st1[4]=(__bf16)f3.x; st1[5]=(__bf16)f3.y; st1[6]=(__bf16)f3.z; st1[7]=(__bf16)f3.w;
    }

    if (tid == 0) nv = 0;
    if (tid < 64) cnt[tid] = 0;
    __syncthreads();

    // compact + histogram in one pass; one nv atomic per wave per round
    {
        const int4* sp = (const int4*)(packed + (size_t)b * SCAT_BLOCKS * CAPC);
        #pragma unroll
        for (int k = 0; k < 4; ++k) {           // ceil(391*4 / 512) = 4 rounds
            int i = k * 512 + tid;
            int4 v; v.x = -1; v.y = -1; v.z = -1; v.w = -1;
            if (i < SCAT_BLOCKS * 4) v = sp[i];
            int c = (v.x != -1) + (v.y != -1) + (v.z != -1) + (v.w != -1);
            int p = c;
            #pragma unroll
            for (int o = 1; o < 64; o <<= 1) {
                int u = __shfl_up(p, o);
                if (lane64 >= o) p += u;
            }
            int wt = __shfl(p, 63);
            int wb = 0;
            if (lane64 == 63 && wt) wb = atomicAdd(&nv, wt);
            wb = __shfl(wb, 63);
            int pos = wb + p - c;
            if (v.x != -1) { if (pos < CAPB) { pk[pos] = v.x; atomicAdd(&cnt[v.x >> 16], 1); } ++pos; }
            if (v.y != -1) { if (pos < CAPB) { pk[pos] = v.y; atomicAdd(&cnt[v.y >> 16], 1); } ++pos; }
            if (v.z != -1) { if (pos < CAPB) { pk[pos] = v.z; atomicAdd(&cnt[v.z >> 16], 1); } ++pos; }
            if (v.w != -1) { if (pos < CAPB) { pk[pos] = v.w; atomicAdd(&cnt[v.w >> 16], 1); } ++pos; }
        }
    }
    __syncthreads();
    const int ecnt = min(nv, CAPB);

    // exclusive scan of pad-to-8 lengths, wave 0 (64 lanes = 64 nodes)
    if (tid < 64) {
        int c = cnt[tid];
        int cp = (c + 7) & ~7;
        int v = cp;
        #pragma unroll
        for (int o = 1; o < 64; o <<= 1) {
            int u = __shfl_up(v, o);
            if (tid >= o) v += u;
        }
        loff[tid] = v - cp;
        degs[tid] = c;
        cnt[tid] = 0;                  // reuse as rank cursor
    }
    __syncthreads();
    // rank-scatter into per-node u16 lists + pad tails with zero row
    for (int i = tid; i < ecnt; i += 512) {
        int p = pk[i];
        int l = p >> 16;
        int r = atomicAdd(&cnt[l], 1);
        srt[loff[l] + r] = (unsigned short)p;     // low 16 bits = src id
    }
    if (tid < 64) {
        int c = degs[tid];
        int cp = (c + 7) & ~7;
        int base0 = loff[tid];
        for (int j = c; j < cp; ++j) srt[base0 + j] = (unsigned short)N_NODES;
    }
    __syncthreads();                   // pk dead from here on

    // stage self rows into At from registers (overlays pk region — safe now)
    *(bf16x8*)&At[srow][scol] = st0;
    *(bf16x8*)&At[srow][scol + 8] = st1;

    // gather-mean from fp8, 16 half-waves x 4 nodes, 8-deep batches.
    {
        const int hw = tid >> 5;          // 0..15
        const int lane = tid & 31;
        const unsigned int* g8 = (const unsigned int*)feat8;
        #pragma unroll
        for (int t = 0; t < 4; ++t) {
            int i = hw + t * 16;
            int dg = degs[i];
            int dgp = (dg + 7) & ~7;
            const int base0 = loff[i];
            float a0 = 0.f, a1 = 0.f, a2 = 0.f, a3 = 0.f;
            for (int j = 0; j < dgp; j += 8) {
                int s[8]; unsigned int w[8];
                #pragma unroll
                for (int q = 0; q < 8; ++q) s[q] = srt[base0 + j + q];
                #pragma unroll
                for (int q = 0; q < 8; ++q)
                    w[q] = g8[(size_t)s[q] * 32 + lane];
                #pragma unroll
                for (int q = 0; q < 8; ++q) {
#ifdef HW_FP8
                    f32x2 lo = __builtin_amdgcn_cvt_pk_f32_fp8((int)w[q], false);
                    f32x2 hi = __builtin_amdgcn_cvt_pk_f32_fp8((int)w[q], true);
                    a0 += lo[0]; a1 += lo[1]; a2 += hi[0]; a3 += hi[1];
#else
                    a0 += fp8tof_sw(w[q] & 0xFF);
                    a1 += fp8tof_sw((w[q] >> 8) & 0xFF);
                    a2 += fp8tof_sw((w[q] >> 16) & 0xFF);
                    a3 += fp8tof_sw(w[q] >> 24);
#endif
                }
            }
            float sc = dg > 0 ? 1.0f / (float)dg : 0.f;   // DGL mean: deg==0 -> 0
            bf16x4 hv;
            hv[0] = (__bf16)(a0 * sc); hv[1] = (__bf16)(a1 * sc);
            hv[2] = (__bf16)(a2 * sc); hv[3] = (__bf16)(a3 * sc);
            *(bf16x4*)&At[i][128 + lane * 4] = hv;
        }
    }
    __syncthreads();

    // K=256 MFMA GEMM. Wave w (0..7): rows (w&1)*32..+32, cols (w>>1)*32..+32.
    const int wv = tid >> 6;
    const int m = lane64 & 15;
    const int quad = lane64 >> 4;
    const int r0 = (wv & 1) * 32;
    const int c0 = (wv >> 1) * 32;

    f32x4 acc[2][2] = {};
    #pragma unroll
    for (int k0 = 0; k0 < 256; k0 += 32) {
        const int kk = k0 + quad * 8;
        bf16x8 a0 = *(const bf16x8*)&At[r0 + m][kk];
        bf16x8 a1 = *(const bf16x8*)&At[r0 + 16 + m][kk];
        #pragma unroll
        for (int ct = 0; ct < 2; ++ct) {
            int col = c0 + ct * 16 + m;
            bf16x8 bb = *(const bf16x8*)(Wc16 + (size_t)col * 256 + kk);
            acc[0][ct] = __builtin_amdgcn_mfma_f32_16x16x32_bf16(a0, bb, acc[0][ct], 0, 0, 0);
            acc[1][ct] = __builtin_amdgcn_mfma_f32_16x16x32_bf16(a1, bb, acc[1][ct], 0, 0, 0);
        }
    }
    __syncthreads();   // done reading At

    // epilogue: transpose-store via Ct overlay (stride 132 f32), float4 stores.
    float* Ct = (float*)smem;
    #pragma unroll
    for (int rt = 0; rt < 2; ++rt) {
        #pragma unroll
        for (int ct = 0; ct < 2; ++ct) {
            int ccol = c0 + ct * 16 + m;
            int crow = r0 + rt * 16 + quad * 4;
            #pragma unroll
            for (int r = 0; r < 4; ++r)
                Ct[(crow + r) * 132 + ccol] = acc[rt][ct][r];
        }
    }
    __syncthreads();
    for (int idx = tid; idx < 64 * 32; idx += 512) {
        int row = idx >> 5;
        int c4 = (idx & 31) * 4;
        int nn = node0 + row;
        if (nn < N_NODES) {
            float4 v = *(float4*)&Ct[row * 132 + c4];
            float4 bb = *(const float4*)(biasc + c4);
            v.x += bb.x; v.y += bb.y; v.z += bb.z; v.w += bb.w;
            *(float4*)&out[(size_t)nn * D + c4] = v;
        }
    }
}

extern "C" void kernel_launch(void* const* d_in, const int* in_sizes, int n_in,
                              void* d_out, int out_size, void* d_ws, size_t ws_size,
                              hipStream_t stream) {
    const float* feat    = (const float*)d_in[0];
    const int*   src     = (const int*)d_in[1];
    const int*   dst     = (const int*)d_in[2];
    const float* W_self  = (const float*)d_in[3];
    const float* b_self  = (const float*)d_in[4];
    const float* W_neigh = (const float*)d_in[5];
    const float* bias    = (const float*)d_in[6];
    float* out = (float*)d_out;
    char*  ws  = (char*)d_ws;

    int* packed  = (int*)(ws + OFF_PACKED);
    unsigned char* feat8 = (unsigned char*)(ws + OFF_FEAT8);
    __bf16* Wc16  = (__bf16*)(ws + OFF_WC16);
    float*  biasc = (float*)(ws + OFF_BIASC);
    const int n_edges = in_sizes[1];

    prep_kernel<<<dim3(SCAT_BLOCKS + FEAT_BLOCKS + W_BLOCKS + 1), 256, 0, stream>>>(
        src, dst, packed, feat, feat8, W_self, W_neigh, b_self, bias,
        Wc16, biasc, n_edges);
    fused_kernel<<<dim3(NBUK), 512, 0, stream>>>(
        feat, feat8, packed, Wc16, biasc, out);
}

// Round 9
// 129.011 us; speedup vs baseline: 2.0572x; 1.0154x over previous
//
#include <hip/hip_runtime.h>
#include <hip/hip_fp8.h>

#define N_NODES 50000
#define N_EDGES 800000
#define D 128
#define NBUK 782         // 64-node dst buckets: ceil(50000/64)
#define CAPB 1344        // per-bucket edge cap (mean ~1023, +10 sigma)
#define SRTN (CAPB + 64*7)   // 1792 u16: pad-to-8 worst case
#define EPB 2048
#define SCAT_BLOCKS 391  // 391*2048 = 800768 >= 800000
#define FEAT_BLOCKS 3125 // 3125*256*8 = 6.4M = 50000*128
#define W_BLOCKS 32
#define CAPC 16          // slots per (bucket, scatter-block) cell = one 64B line

typedef __bf16 bf16x8 __attribute__((ext_vector_type(8)));
typedef __bf16 bf16x4 __attribute__((ext_vector_type(4)));
typedef float  f32x4  __attribute__((ext_vector_type(4)));
typedef float  f32x2  __attribute__((ext_vector_type(2)));

#if defined(__has_builtin)
#if __has_builtin(__builtin_amdgcn_cvt_pk_f32_fp8) && __has_builtin(__builtin_amdgcn_cvt_pk_fp8_f32)
#define HW_FP8 1
#endif
#endif

// ws layout (bytes), audited (R6 lesson). No memset needed.
//   packed @ 0          [782*391 cells * 64 B = 19,568,768]
//   feat8  @ 19,568,768 [50001*128 u8 = 6,400,128] -> 25,968,896
//   Wc16   @ 25,968,896 [32768 bf16 = 65,536] -> 26,034,432
//   biasc  @ 26,034,432 [512] -> 26,034,944
//   feat16 @ 26,035,200 [50000*128 bf16 = 12,800,000] -> 38,835,200
#define OFF_PACKED 0ull
#define OFF_FEAT8  19568768ull
#define OFF_WC16   25968896ull
#define OFF_BIASC  26034432ull
#define OFF_FEAT16 26035200ull

__device__ __forceinline__ float fp8tof_sw(unsigned char b) {
    __hip_fp8_e4m3 t; t.__x = b;
    return (float)t;
}

// ---- prep: deterministic stripe scatter (ZERO global atomics)
//            || feat->fp8+bf16 || weights || bias ------------------------
__global__ __launch_bounds__(256)
void prep_kernel(const int* __restrict__ src, const int* __restrict__ dst,
                 int* __restrict__ packed,
                 const float* __restrict__ feat, unsigned char* __restrict__ feat8,
                 __bf16* __restrict__ feat16,
                 const float* __restrict__ Ws, const float* __restrict__ Wn,
                 const float* __restrict__ b_self, const float* __restrict__ bias,
                 __bf16* __restrict__ Wc16, float* __restrict__ biasc, int n) {
    const int tid = threadIdx.x;
    const int bid = blockIdx.x;
    if (bid < SCAT_BLOCKS) {
        __shared__ int hist[NBUK];     // histogram, then rank cursor
        __shared__ int boff[NBUK];     // exclusive offsets into srtL
        __shared__ int srtL[EPB];      // block's edges sorted by bucket
        __shared__ int wtot[4];
        const int e0 = bid * EPB;
        int d[8], s[8];
        for (int i = tid; i < NBUK; i += 256) hist[i] = 0;
        __syncthreads();
        // pass A: histogram; keep (d,s) in registers
        #pragma unroll
        for (int j = 0; j < 8; ++j) {
            int e = e0 + j * 256 + tid;
            bool ok = e < n;
            d[j] = ok ? dst[e] : -1;
            s[j] = ok ? src[e] : 0;
            if (ok) atomicAdd(&hist[d[j] >> 6], 1);
        }
        __syncthreads();
        // block-wide exclusive scan over 782 buckets (4 buckets/thread)
        {
            const int lane = tid & 63;
            const int wv = tid >> 6;
            const int b4 = tid * 4;
            int h0 = (b4 + 0 < NBUK) ? hist[b4 + 0] : 0;
            int h1 = (b4 + 1 < NBUK) ? hist[b4 + 1] : 0;
            int h2 = (b4 + 2 < NBUK) ? hist[b4 + 2] : 0;
            int h3 = (b4 + 3 < NBUK) ? hist[b4 + 3] : 0;
            int sm = h0 + h1 + h2 + h3;
            int v = sm;
            #pragma unroll
            for (int o = 1; o < 64; o <<= 1) {
                int u = __shfl_up(v, o);
                if (lane >= o) v += u;
            }
            if (lane == 63) wtot[wv] = v;
            __syncthreads();
            if (tid == 0) {
                int r = 0;
                #pragma unroll
                for (int j = 0; j < 4; ++j) { int t = wtot[j]; wtot[j] = r; r += t; }
            }
            __syncthreads();
            int ex = wtot[wv] + v - sm;       // exclusive prefix of this group
            if (b4 + 0 < NBUK) { boff[b4 + 0] = ex;                hist[b4 + 0] = 0; }
            if (b4 + 1 < NBUK) { boff[b4 + 1] = ex + h0;           hist[b4 + 1] = 0; }
            if (b4 + 2 < NBUK) { boff[b4 + 2] = ex + h0 + h1;      hist[b4 + 2] = 0; }
            if (b4 + 3 < NBUK) { boff[b4 + 3] = ex + h0 + h1 + h2; hist[b4 + 3] = 0; }
        }
        __syncthreads();
        // rank-scatter into bucket-sorted LDS list
        #pragma unroll
        for (int j = 0; j < 8; ++j) {
            if (d[j] >= 0) {
                int bk = d[j] >> 6;
                int r = atomicAdd(&hist[bk], 1);
                srtL[boff[bk] + r] = ((d[j] & 63) << 16) | s[j];
            }
        }
        __syncthreads();
        // write-out: one 64B cell per bucket, fully written (sentinel pad)
        for (int idx = tid; idx < NBUK * 4; idx += 256) {
            int bk = idx >> 2;
            int q4 = (idx & 3) * 4;
            int off = boff[bk];
            int c = hist[bk];
            int4 v;
            v.x = (q4 + 0 < c) ? srtL[off + q4 + 0] : -1;
            v.y = (q4 + 1 < c) ? srtL[off + q4 + 1] : -1;
            v.z = (q4 + 2 < c) ? srtL[off + q4 + 2] : -1;
            v.w = (q4 + 3 < c) ? srtL[off + q4 + 3] : -1;
            *(int4*)&packed[((size_t)bk * SCAT_BLOCKS + bid) * CAPC + q4] = v;
        }
    } else if (bid < SCAT_BLOCKS + FEAT_BLOCKS) {
        size_t i = ((size_t)(bid - SCAT_BLOCKS) * 256 + tid) * 8;
        float4 f0 = *(const float4*)(feat + i);
        float4 f1 = *(const float4*)(feat + i + 4);
        bf16x8 t16;
        t16[0]=(__bf16)f0.x; t16[1]=(__bf16)f0.y; t16[2]=(__bf16)f0.z; t16[3]=(__bf16)f0.w;
        t16[4]=(__bf16)f1.x; t16[5]=(__bf16)f1.y; t16[6]=(__bf16)f1.z; t16[7]=(__bf16)f1.w;
        *(bf16x8*)(feat16 + i) = t16;
#ifdef HW_FP8
        int q0 = __builtin_amdgcn_cvt_pk_fp8_f32(f0.x, f0.y, 0, false);
        q0     = __builtin_amdgcn_cvt_pk_fp8_f32(f0.z, f0.w, q0, true);
        int q1 = __builtin_amdgcn_cvt_pk_fp8_f32(f1.x, f1.y, 0, false);
        q1     = __builtin_amdgcn_cvt_pk_fp8_f32(f1.z, f1.w, q1, true);
        uint2 qq; qq.x = (unsigned)q0; qq.y = (unsigned)q1;
        *(uint2*)(feat8 + i) = qq;
#else
        float fv[8] = {f0.x, f0.y, f0.z, f0.w, f1.x, f1.y, f1.z, f1.w};
        union { unsigned char b[8]; unsigned long long u; } q;
        #pragma unroll
        for (int j = 0; j < 8; ++j) { __hip_fp8_e4m3 e(fv[j]); q.b[j] = e.__x; }
        *(unsigned long long*)(feat8 + i) = q.u;
#endif
    } else if (bid < SCAT_BLOCKS + FEAT_BLOCKS + W_BLOCKS) {
        int idx = (bid - SCAT_BLOCKS - FEAT_BLOCKS) * 256 + tid;   // < 8192
        int col = idx >> 6;
        int kq  = (idx & 63) * 4;
        const float* srcp = (kq < D) ? (Ws + (size_t)col * D + kq)
                                     : (Wn + (size_t)col * D + (kq - D));
        float4 f = *(const float4*)srcp;
        bf16x4 t;
        t[0]=(__bf16)f.x; t[1]=(__bf16)f.y; t[2]=(__bf16)f.z; t[3]=(__bf16)f.w;
        *(bf16x4*)(Wc16 + (size_t)col * 256 + kq) = t;
    } else {
        if (tid < D) biasc[tid] = b_self[tid] + bias[tid];
        else if (tid < D + 32)   // fp8 zero row (index N_NODES)
            ((unsigned*)(feat8 + (size_t)N_NODES * D))[tid - 128] = 0u;
    }
}

// ---- fused: one block per 64-node bucket, 512 threads, 4 blocks/CU.
// Stripe cells held in REGISTERS across hist->scan->scatter (no pk, no
// compact, no nv atomics). 4 barriers total. Direct-register epilogue.
__global__ __launch_bounds__(512)
void fused_kernel(const __bf16* __restrict__ feat16,
                  const unsigned char* __restrict__ feat8,
                  const int* __restrict__ packed,
                  const __bf16* __restrict__ Wc16,
                  const float* __restrict__ biasc,
                  float* __restrict__ out) {
    __shared__ __bf16 At[64][264];          // 33,792 B
    __shared__ unsigned short srt[SRTN];    // 3,584 B
    __shared__ int cnt[64];
    __shared__ int loff[64];
    __shared__ int degs[64];
    const int tid = threadIdx.x;
    const int b = blockIdx.x;
    const int node0 = b * 64;

    // T14: issue self-row bf16 loads now; consume after the sort.
    const int srow = tid >> 3;
    const int scol = (tid & 7) * 16;
    const int snn = node0 + srow;
    bf16x8 st0 = {}, st1 = {};
    if (snn < N_NODES) {
        const __bf16* sp = feat16 + (size_t)snn * D + scol;
        st0 = *(const bf16x8*)sp;
        st1 = *(const bf16x8*)(sp + 8);
    }

    if (tid < 64) cnt[tid] = 0;
    __syncthreads();

    // stripe read -> registers (4 x int4, static indices) + histogram
    int4 vv0, vv1, vv2, vv3;
    {
        const int4* sp = (const int4*)(packed + (size_t)b * SCAT_BLOCKS * CAPC);
        int4 none; none.x = -1; none.y = -1; none.z = -1; none.w = -1;
        int i0 = tid, i1 = 512 + tid, i2 = 1024 + tid, i3 = 1536 + tid;
        vv0 = sp[i0];                                   // 1564 cells: i0..i2 valid
        vv1 = sp[i1];
        vv2 = (i2 < SCAT_BLOCKS * 4) ? sp[i2] : none;
        vv3 = (i3 < SCAT_BLOCKS * 4) ? sp[i3] : none;
        #define HISTV(v) do { \
            if ((v).x != -1) atomicAdd(&cnt[(v).x >> 16], 1); \
            if ((v).y != -1) atomicAdd(&cnt[(v).y >> 16], 1); \
            if ((v).z != -1) atomicAdd(&cnt[(v).z >> 16], 1); \
            if ((v).w != -1) atomicAdd(&cnt[(v).w >> 16], 1); } while (0)
        HISTV(vv0); HISTV(vv1); HISTV(vv2); HISTV(vv3);
        #undef HISTV
    }
    __syncthreads();

    // exclusive scan of pad-to-8 lengths, wave 0 (64 lanes = 64 nodes)
    if (tid < 64) {
        int c = cnt[tid];
        int cp = (c + 7) & ~7;
        int v = cp;
        #pragma unroll
        for (int o = 1; o < 64; o <<= 1) {
            int u = __shfl_up(v, o);
            if (tid >= o) v += u;
        }
        loff[tid] = v - cp;
        degs[tid] = c;
        cnt[tid] = 0;                  // reuse as rank cursor
    }
    __syncthreads();

    // stage self rows + rank-scatter from registers + pad tails
    *(bf16x8*)&At[srow][scol] = st0;
    *(bf16x8*)&At[srow][scol + 8] = st1;
    {
        #define SCATV(v) do { \
            if ((v).x != -1) { int l = (v).x >> 16; int r = atomicAdd(&cnt[l], 1); int o = loff[l] + r; if (o < SRTN) srt[o] = (unsigned short)(v).x; } \
            if ((v).y != -1) { int l = (v).y >> 16; int r = atomicAdd(&cnt[l], 1); int o = loff[l] + r; if (o < SRTN) srt[o] = (unsigned short)(v).y; } \
            if ((v).z != -1) { int l = (v).z >> 16; int r = atomicAdd(&cnt[l], 1); int o = loff[l] + r; if (o < SRTN) srt[o] = (unsigned short)(v).z; } \
            if ((v).w != -1) { int l = (v).w >> 16; int r = atomicAdd(&cnt[l], 1); int o = loff[l] + r; if (o < SRTN) srt[o] = (unsigned short)(v).w; } } while (0)
        SCATV(vv0); SCATV(vv1); SCATV(vv2); SCATV(vv3);
        #undef SCATV
    }
    if (tid < 64) {
        int c = degs[tid];
        int cp = (c + 7) & ~7;
        int base0 = loff[tid];
        for (int j = c; j < cp; ++j)
            if (base0 + j < SRTN) srt[base0 + j] = (unsigned short)N_NODES;
    }
    __syncthreads();

    // gather-mean from fp8, 16 half-waves x 4 nodes, 8-deep batches.
    {
        const int hw = tid >> 5;          // 0..15
        const int lane = tid & 31;
        const unsigned int* g8 = (const unsigned int*)feat8;
        #pragma unroll
        for (int t = 0; t < 4; ++t) {
            int i = hw + t * 16;
            int dg = degs[i];
            int dgp = (dg + 7) & ~7;
            const int base0 = loff[i];
            float a0 = 0.f, a1 = 0.f, a2 = 0.f, a3 = 0.f;
            for (int j = 0; j < dgp; j += 8) {
                int s[8]; unsigned int w[8];
                #pragma unroll
                for (int q = 0; q < 8; ++q) s[q] = srt[base0 + j + q];
                #pragma unroll
                for (int q = 0; q < 8; ++q)
                    w[q] = g8[(size_t)s[q] * 32 + lane];
                #pragma unroll
                for (int q = 0; q < 8; ++q) {
#ifdef HW_FP8
                    f32x2 lo = __builtin_amdgcn_cvt_pk_f32_fp8((int)w[q], false);
                    f32x2 hi = __builtin_amdgcn_cvt_pk_f32_fp8((int)w[q], true);
                    a0 += lo[0]; a1 += lo[1]; a2 += hi[0]; a3 += hi[1];
#else
                    a0 += fp8tof_sw(w[q] & 0xFF);
                    a1 += fp8tof_sw((w[q] >> 8) & 0xFF);
                    a2 += fp8tof_sw((w[q] >> 16) & 0xFF);
                    a3 += fp8tof_sw(w[q] >> 24);
#endif
                }
            }
            float sc = dg > 0 ? 1.0f / (float)dg : 0.f;   // DGL mean: deg==0 -> 0
            bf16x4 hv;
            hv[0] = (__bf16)(a0 * sc); hv[1] = (__bf16)(a1 * sc);
            hv[2] = (__bf16)(a2 * sc); hv[3] = (__bf16)(a3 * sc);
            *(bf16x4*)&At[i][128 + lane * 4] = hv;
        }
    }
    __syncthreads();

    // K=256 MFMA GEMM. Wave w (0..7): rows (w&1)*32..+32, cols (w>>1)*32..+32.
    const int wv = tid >> 6;
    const int lane = tid & 63;
    const int m = lane & 15;
    const int quad = lane >> 4;
    const int r0 = (wv & 1) * 32;
    const int c0 = (wv >> 1) * 32;

    f32x4 acc[2][2] = {};
    #pragma unroll
    for (int k0 = 0; k0 < 256; k0 += 32) {
        const int kk = k0 + quad * 8;
        bf16x8 a0 = *(const bf16x8*)&At[r0 + m][kk];
        bf16x8 a1 = *(const bf16x8*)&At[r0 + 16 + m][kk];
        #pragma unroll
        for (int ct = 0; ct < 2; ++ct) {
            int col = c0 + ct * 16 + m;
            bf16x8 bb = *(const bf16x8*)(Wc16 + (size_t)col * 256 + kk);
            acc[0][ct] = __builtin_amdgcn_mfma_f32_16x16x32_bf16(a0, bb, acc[0][ct], 0, 0, 0);
            acc[1][ct] = __builtin_amdgcn_mfma_f32_16x16x32_bf16(a1, bb, acc[1][ct], 0, 0, 0);
        }
    }

    // direct-register epilogue: bias + store (no LDS round-trip, no barriers)
    #pragma unroll
    for (int ct = 0; ct < 2; ++ct) {
        int col = c0 + ct * 16 + m;
        float bb = biasc[col];
        #pragma unroll
        for (int rt = 0; rt < 2; ++rt) {
            int rowb = node0 + r0 + rt * 16 + quad * 4;
            #pragma unroll
            for (int r = 0; r < 4; ++r) {
                int nn = rowb + r;
                if (nn < N_NODES)
                    out[(size_t)nn * D + col] = acc[rt][ct][r] + bb;
            }
        }
    }
}

extern "C" void kernel_launch(void* const* d_in, const int* in_sizes, int n_in,
                              void* d_out, int out_size, void* d_ws, size_t ws_size,
                              hipStream_t stream) {
    const float* feat    = (const float*)d_in[0];
    const int*   src     = (const int*)d_in[1];
    const int*   dst     = (const int*)d_in[2];
    const float* W_self  = (const float*)d_in[3];
    const float* b_self  = (const float*)d_in[4];
    const float* W_neigh = (const float*)d_in[5];
    const float* bias    = (const float*)d_in[6];
    float* out = (float*)d_out;
    char*  ws  = (char*)d_ws;

    int* packed  = (int*)(ws + OFF_PACKED);
    unsigned char* feat8 = (unsigned char*)(ws + OFF_FEAT8);
    __bf16* Wc16   = (__bf16*)(ws + OFF_WC16);
    float*  biasc  = (float*)(ws + OFF_BIASC);
    __bf16* feat16 = (__bf16*)(ws + OFF_FEAT16);
    const int n_edges = in_sizes[1];

    prep_kernel<<<dim3(SCAT_BLOCKS + FEAT_BLOCKS + W_BLOCKS + 1), 256, 0, stream>>>(
        src, dst, packed, feat, feat8, feat16, W_self, W_neigh, b_self, bias,
        Wc16, biasc, n_edges);
    fused_kernel<<<dim3(NBUK), 512, 0, stream>>>(
        feat16, feat8, packed, Wc16, biasc, out);
}